// Round 10
// baseline (185.745 us; speedup 1.0000x reference)
//
#include <hip/hip_runtime.h>

#define NB    32
#define CIN   64
#define COUT  128
#define HH    56
#define WW    56
#define HP    58
#define NPIX  (NB*HH*WW)
#define BN_EPSF 1e-5f
#define NXPAD (NB*CIN*HP*HP)     // 6,889,472 padded bf16 elems

typedef __bf16 bf16x8 __attribute__((ext_vector_type(8)));
typedef float  f32x4  __attribute__((ext_vector_type(4)));

// ---- prep: x -> zero-padded NCHW bf16; assemble block-diag w; zero stats ----
__global__ __launch_bounds__(256) void prep(
    const float* __restrict__ x, const float* __restrict__ wb,
    __bf16* __restrict__ xpad, __bf16* __restrict__ whi, float* __restrict__ stats)
{
    int idx = blockIdx.x * 256 + threadIdx.x;
    if (idx < NXPAD) {
        int wp = idx % HP, r = idx / HP;
        int hp = r % HP, ci = r / HP;            // ci = n*64+ic
        __bf16 v = (__bf16)0.0f;
        if (hp >= 1 && hp <= HH && wp >= 1 && wp <= WW)
            v = (__bf16)x[(ci * HH + (hp - 1)) * WW + (wp - 1)];
        xpad[idx] = v;
        return;
    }
    idx -= NXPAD;
    if (idx < 576 * 128) {
        int col = idx >> 7, oc = idx & 127;      // col = ic*9 + kh*3 + kw
        int p = oc >> 3, i = oc & 7, q = col >> 3, j = col & 7;
        float v = wb[((p * 72 + q) * 8 + i) * 8 + j];
        int ic = col / 9, tap = col % 9;
        int dst = ((tap * 2 + (ic >> 5)) * 128 + oc) * 32 + (ic & 31);
        whi[dst] = (__bf16)v;
        return;
    }
    idx -= 576 * 128;
    if (idx < 256) stats[idx] = 0.0f;            // gsum[128] | gsq[128]
}

// ---------------- MFMA conv: weights in NAMED registers (rule #20 fix) -------
// block: image n, 8x8 px tile, 64-oc half. 4 waves x 16 oc.
// K-loop: 72 ds_read_b128 + 72 MFMA per wave, fully unrolled, no barriers,
// no global loads. B-fragments = 18 named bf16x8 (72 VGPR, SROA-promotable).
__global__ __launch_bounds__(256, 4) void conv_mfma(
    const __bf16* __restrict__ xpad, const __bf16* __restrict__ whi,
    float* __restrict__ y, float* __restrict__ gsum, float* __restrict__ gsq)
{
    __shared__ __bf16 xs[100 * 64];      // [halo px 10x10][64 ic], swizzled

    int b = blockIdx.x;
    int ocb = b & 1;                     // oc half: 0 -> 0..63, 1 -> 64..127
    int tile = b >> 1;
    int n = tile / 49, t = tile % 49;
    int h0 = (t / 7) * 8, w0 = (t % 7) * 8;
    int tid  = threadIdx.x;
    int lane = tid & 63, wid = tid >> 6;
    int l15 = lane & 15, l4 = lane >> 4;
    int oc0 = ocb * 64 + wid * 16;

    // ---- all K=576 B-fragments for this wave's 16 oc: 18 NAMED bf16x8 ----
    int woff = (oc0 + l15) * 32 + l4 * 8;
#define BLOAD(i) const bf16x8 B##i = *(const bf16x8*)&whi[(i) * 4096 + woff]
    BLOAD(0);  BLOAD(1);  BLOAD(2);  BLOAD(3);  BLOAD(4);  BLOAD(5);
    BLOAD(6);  BLOAD(7);  BLOAD(8);  BLOAD(9);  BLOAD(10); BLOAD(11);
    BLOAD(12); BLOAD(13); BLOAD(14); BLOAD(15); BLOAD(16); BLOAD(17);
#undef BLOAD

    // ---- stage x halo: thread = (chunk c of 8 ic, px); swizzled 16B writes
    const __bf16* xn = xpad + n * CIN * HP * HP;
    for (int u = tid; u < 800; u += 256) {
        int c = u / 100, px = u - c * 100;
        int r = px / 10, cc = px - r * 10;
        const __bf16* src = xn + (c * 8) * (HP * HP) + (h0 + r) * HP + (w0 + cc);
        bf16x8 hv;
        #pragma unroll
        for (int j = 0; j < 8; ++j) hv[j] = src[j * HP * HP];
        *(bf16x8*)&xs[px * 64 + ((c ^ (px & 7)) * 8)] = hv;
    }
    __syncthreads();

    f32x4 acc0 = {}, acc1 = {}, acc2 = {}, acc3 = {};
    int rb0 = (l15 >> 3) * 10 + (l15 & 7);       // halo row*10+col base

#define KS1(BI, TOFF, C0, MT, ACC) { \
        int R  = rb0 + (MT) * 20 + (TOFF); \
        int ae = R * 64 + (((C0) ^ (R & 7)) * 8); \
        bf16x8 a = *(const bf16x8*)&xs[ae]; \
        ACC = __builtin_amdgcn_mfma_f32_16x16x32_bf16(a, BI, ACC, 0, 0, 0); }
#define KS(BI, TOFF, HALF) { \
        const int c0 = (HALF) * 4 + l4; \
        KS1(BI, TOFF, c0, 0, acc0) KS1(BI, TOFF, c0, 1, acc1) \
        KS1(BI, TOFF, c0, 2, acc2) KS1(BI, TOFF, c0, 3, acc3) }

    // th = tap*2+half; toff = (tap/3)*10 + tap%3
    KS(B0,  0, 0) KS(B1,  0, 1) KS(B2,  1, 0) KS(B3,  1, 1)
    KS(B4,  2, 0) KS(B5,  2, 1) KS(B6, 10, 0) KS(B7, 10, 1)
    KS(B8, 11, 0) KS(B9, 11, 1) KS(B10,12, 0) KS(B11,12, 1)
    KS(B12,20, 0) KS(B13,20, 1) KS(B14,21, 0) KS(B15,21, 1)
    KS(B16,22, 0) KS(B17,22, 1)
#undef KS
#undef KS1

    // ---- write raw y (pre-BN): float4 per mt ----
    // C/D layout: col(oc_local)=lane&15, row(M-local)=(lane>>4)*4 + reg  [m89]
    float* yn = y + n * COUT * HH * WW;
    int pyb = l4 >> 1;
    int gwo = w0 + (l4 & 1) * 4;
    int oc  = oc0 + l15;
    {
        int gh0 = h0 + pyb;
        *(float4*)&yn[(oc * HH + gh0    ) * WW + gwo] = *(float4*)&acc0;
        *(float4*)&yn[(oc * HH + gh0 + 2) * WW + gwo] = *(float4*)&acc1;
        *(float4*)&yn[(oc * HH + gh0 + 4) * WW + gwo] = *(float4*)&acc2;
        *(float4*)&yn[(oc * HH + gh0 + 6) * WW + gwo] = *(float4*)&acc3;
    }

    // ---- per-channel partial stats; red aliases xs (all xs reads done) ----
    float* red = (float*)xs;
    float s = 0.0f, sq = 0.0f;
    #pragma unroll
    for (int r = 0; r < 4; ++r) {
        float v0 = acc0[r], v1 = acc1[r], v2 = acc2[r], v3 = acc3[r];
        s  += v0 + v1 + v2 + v3;
        sq += v0 * v0 + v1 * v1 + v2 * v2 + v3 * v3;
    }
    s  += __shfl_xor(s, 16, 64);  s  += __shfl_xor(s, 32, 64);
    sq += __shfl_xor(sq, 16, 64); sq += __shfl_xor(sq, 32, 64);
    __syncthreads();
    if (l4 == 0) {
        int o = wid * 16 + l15;
        red[o] = s; red[64 + o] = sq;
    }
    __syncthreads();
    if (tid < 64) {
        atomicAdd(&gsum[ocb * 64 + tid], red[tid]);
        atomicAdd(&gsq [ocb * 64 + tid], red[64 + tid]);
    }
}

// -------- BN finalize (inline, per block) + apply + clip, in-place ----------
__global__ __launch_bounds__(256) void bn_apply(float* __restrict__ y,
        const float* __restrict__ gsum, const float* __restrict__ gsq,
        const float* __restrict__ gamma, const float* __restrict__ beta)
{
    __shared__ float ssc[128], ssh[128];
    int tid = threadIdx.x;
    if (tid < 128) {
        float mean = gsum[tid] * (1.0f / NPIX);
        float var  = gsq[tid]  * (1.0f / NPIX) - mean * mean;
        float inv  = gamma[tid] / sqrtf(var + BN_EPSF);
        ssc[tid] = inv;
        ssh[tid] = beta[tid] - mean * inv;
    }
    __syncthreads();

    const int total4 = NB * COUT * HH * WW / 4;   // 3,211,264
    int idx = blockIdx.x * blockDim.x + tid;
    int stride = gridDim.x * blockDim.x;
    for (int i4 = idx; i4 < total4; i4 += stride) {
        int c = (i4 / 784) & 127;                 // 784 float4 per channel plane
        float sc = ssc[c], sh = ssh[c];
        float4 v = ((float4*)y)[i4];
        v.x = fminf(fmaxf(fmaf(v.x, sc, sh), 0.0f), 6.0f);
        v.y = fminf(fmaxf(fmaf(v.y, sc, sh), 0.0f), 6.0f);
        v.z = fminf(fmaxf(fmaf(v.z, sc, sh), 0.0f), 6.0f);
        v.w = fminf(fmaxf(fmaf(v.w, sc, sh), 0.0f), 6.0f);
        ((float4*)y)[i4] = v;
    }
}

extern "C" void kernel_launch(void* const* d_in, const int* in_sizes, int n_in,
                              void* d_out, int out_size, void* d_ws, size_t ws_size,
                              hipStream_t stream) {
    const float* x     = (const float*)d_in[0];
    const float* wb    = (const float*)d_in[1];
    const float* gamma = (const float*)d_in[2];
    const float* beta  = (const float*)d_in[3];
    float* y = (float*)d_out;

    __bf16* xpad  = (__bf16*)d_ws;               // 6,889,472 bf16 = 13.78 MB
    __bf16* whi   = xpad + NXPAD;                // 73728 bf16
    float*  stats = (float*)(whi + 73728);       // 256 floats (gsum|gsq)
    float*  gsum  = stats;
    float*  gsq   = stats + 128;

    int prep_grid = (NXPAD + 576 * 128 + 256 + 255) / 256;   // 27201
    prep<<<prep_grid, 256, 0, stream>>>(x, wb, xpad, whi, stats);
    conv_mfma<<<NB * 49 * 2, 256, 0, stream>>>(xpad, whi, y, gsum, gsq);
    bn_apply<<<2048, 256, 0, stream>>>(y, gsum, gsq, gamma, beta);
}